// Round 11
// baseline (3478.476 us; speedup 1.0000x reference)
//
#include <hip/hip_runtime.h>
#include <cstdint>

typedef short bf16x8 __attribute__((ext_vector_type(8)));
typedef float f32x4 __attribute__((ext_vector_type(4)));
typedef unsigned u32x2 __attribute__((ext_vector_type(2)));
typedef int i32x2 __attribute__((ext_vector_type(2)));

__device__ __forceinline__ unsigned short f2bf(float f){
  unsigned u = __float_as_uint(f);
  u = u + 0x7fffu + ((u >> 16) & 1u);      // RNE
  return (unsigned short)(u >> 16);
}
__device__ __forceinline__ float bf2f(unsigned short h){
  return __uint_as_float(((unsigned)h) << 16);
}

__device__ __forceinline__ void gld_lds16(const void* g, void* l){
  __builtin_amdgcn_global_load_lds((const __attribute__((address_space(1))) unsigned*)g,
                                   (__attribute__((address_space(3))) unsigned*)l, 16, 0, 0);
}

// L2-bypassing (LLC-coherent) ops — used ONLY for publish + flag polling
__device__ __forceinline__ i32x2 gload8i_cc_wait(const void* p){
  i32x2 r;
  asm volatile("global_load_dwordx2 %0, %1, off sc0 sc1\n\ts_waitcnt vmcnt(0)"
               : "=v"(r) : "v"(p) : "memory");
  return r;
}
__device__ __forceinline__ void gstore8_cc(void* p, u32x2 v){
  asm volatile("global_store_dwordx2 %0, %1, off sc0 sc1" :: "v"(p), "v"(v) : "memory");
}
__device__ __forceinline__ void wait_vm0(){
  asm volatile("s_waitcnt vmcnt(0)" ::: "memory");
  __builtin_amdgcn_sched_barrier(0);
}

// all 128 flags (int) >= t ; each lane checks 2 via one dwordx2
__device__ __forceinline__ void pollwait(const int* f, int t, int lane){
  for (;;){
    i32x2 v = gload8i_cc_wait(f + lane * 2);
    if (__all(v.x >= t && v.y >= t)) break;
    __builtin_amdgcn_s_sleep(2);
  }
}
// merged dual poll: all fA >= tA AND all fB >= tB, ONE LLC round-trip per iteration
__device__ __forceinline__ void pollwait2(const int* fA, int tA, const int* fB, int tB, int lane){
  const int* pa = fA + lane * 2;
  const int* pb = fB + lane * 2;
  for (;;){
    i32x2 a, b;
    asm volatile("global_load_dwordx2 %0, %2, off sc0 sc1\n\t"
                 "global_load_dwordx2 %1, %3, off sc0 sc1\n\t"
                 "s_waitcnt vmcnt(0)"
                 : "=&v"(a), "=&v"(b) : "v"(pa), "v"(pb) : "memory");
    if (__all(a.x >= tA && a.y >= tA && b.x >= tB && b.y >= tB)) break;
    __builtin_amdgcn_s_sleep(2);
  }
}

// ---------------- elementwise f32 -> bf16 cast ----------------
__global__ __launch_bounds__(256)
void k_cast(const float* __restrict__ in, unsigned short* __restrict__ out, int n){
  int i = (blockIdx.x * 256 + threadIdx.x) * 4;
  if (i + 3 < n){
    float4 v = *(const float4*)(in + i);
    ushort4 u;
    u.x = f2bf(v.x); u.y = f2bf(v.y); u.z = f2bf(v.z); u.w = f2bf(v.w);
    *(ushort4*)(out + i) = u;
  }
}

// ---------------- cast f32 [4096][1024] into bf16 [4096][2048] at column offset ----------------
__global__ __launch_bounds__(256)
void k_cast2(const float* __restrict__ in, unsigned short* __restrict__ out, int coloff){
  int i = (blockIdx.x * 256 + threadIdx.x) * 4;
  if (i + 3 < 4194304){
    float4 v = *(const float4*)(in + i);
    ushort4 u;
    u.x = f2bf(v.x); u.y = f2bf(v.y); u.z = f2bf(v.z); u.w = f2bf(v.w);
    int r = i >> 10, c = i & 1023;
    *(ushort4*)(out + (size_t)r * 2048 + coloff + c) = u;
  }
}

// ---------------- transpose + cast: in f32 [R][C] -> out bf16 [C][R] ----------------
__global__ __launch_bounds__(256)
void k_transpose_cast(const float* __restrict__ in, unsigned short* __restrict__ out,
                      int R, int C){
  __shared__ float tile[32][33];
  int tpr = C >> 5;
  int r0 = (blockIdx.x / tpr) * 32, c0 = (blockIdx.x % tpr) * 32;
  int lc = threadIdx.x & 31, lr = threadIdx.x >> 5;
  #pragma unroll
  for (int it = 0; it < 4; ++it)
    tile[lr + it*8][lc] = in[(size_t)(r0 + lr + it*8) * C + c0 + lc];
  __syncthreads();
  #pragma unroll
  for (int it = 0; it < 4; ++it){
    int oc = lr + it*8;
    out[(size_t)(c0 + oc) * R + r0 + lc] = f2bf(tile[lc][oc]);
  }
}

// ---------------- embedding gather: xp0[t][r][b] = Wt0[x[b][t]][r] (bf16) ----------------
__global__ __launch_bounds__(256)
void k_gather(const unsigned short* __restrict__ Wt0, const int* __restrict__ x,
              unsigned short* __restrict__ xp){
  __shared__ unsigned short tile[32][520];
  __shared__ int tok[32];
  const int tid = threadIdx.x;
  const int t = blockIdx.x >> 3, rbase = (blockIdx.x & 7) * 512;
  if (tid < 32) tok[tid] = x[tid * 512 + t];
  __syncthreads();
  for (int b = 0; b < 32; ++b){
    unsigned v = *(const unsigned*)(Wt0 + (size_t)tok[b] * 4096 + rbase + tid * 2);
    *(unsigned*)&tile[b][tid * 2] = v;
  }
  __syncthreads();
  #pragma unroll
  for (int i = 0; i < 2; ++i){
    int rl = tid + i * 256;
    unsigned short vals[32];
    #pragma unroll
    for (int b = 0; b < 32; ++b) vals[b] = tile[b][rl];
    char* dst = (char*)xp + ((size_t)t * 131072 + (size_t)(rbase + rl) * 32) * 2;
    #pragma unroll
    for (int q = 0; q < 4; ++q){
      uint4 w;
      w.x = (unsigned)vals[q*8+0] | ((unsigned)vals[q*8+1] << 16);
      w.y = (unsigned)vals[q*8+2] | ((unsigned)vals[q*8+3] << 16);
      w.z = (unsigned)vals[q*8+4] | ((unsigned)vals[q*8+5] << 16);
      w.w = (unsigned)vals[q*8+6] | ((unsigned)vals[q*8+7] << 16);
      *(uint4*)(dst + q * 16) = w;
    }
  }
}

// ---------------- fused persistent 2-layer LSTM ----------------
// 256 blocks x 512 thr, 1 block/CU (128KB LDS). Blocks 0..127: layer 0 (K=1024).
// Blocks 128..255: layer 1 (K=2048, B=[h1[t]; h2[t-1]], W=[W_ih1|W_hh1] packed).
// Publish: sc0sc1 8B packed stores (write-through to LLC). Consumer staging: NORMAL
// CACHED global_load_lds -> each XCD's L2 serves its ~32 blocks.
// CHANGE vs R10 champion (single, isolated): L1's two sequential pollwait calls
// merged into one pollwait2 (one LLC round-trip instead of two on the critical loop).
// Everything else byte-identical. Flags: round-3 proven protocol.
template<int L1R>
__device__ __forceinline__ void run_lstm5(
    const unsigned short* __restrict__ Wb,      // bf16 [4096][KE]
    const unsigned short* __restrict__ xp,      // L0 only
    const float* __restrict__ b_ih, const float* __restrict__ b_hh,
    unsigned short* __restrict__ h_self,        // own layer output [512][32][1024]
    const unsigned short* __restrict__ h_in,    // L1: h1seq
    int* __restrict__ flag_self, const int* __restrict__ flag_in,
    int jslot, char* lds)
{
  constexpr int KE  = L1R ? 2048 : 1024;   // K elems
  constexpr int RS  = KE * 2;              // row stride bytes (W and LDS tile)
  constexpr int KB2 = KE / 64;             // MFMA k-steps per wave (K split by 2)

  const int tid = threadIdx.x, lane = tid & 63, wv = tid >> 6;
  const int wv_k = wv & 1, wv_b = (wv >> 1) & 1, wv_m = wv >> 2;
  const int l15 = lane & 15, l4 = (lane >> 4) & 3;
  const int jbase = jslot * 8;

  // A fragments in registers: slice rows wv_m*16..+16, K half wv_k
  bf16x8 afr[KB2];
  {
    const int ar = wv_m * 16 + l15;
    const int grow = (ar >> 3) * 1024 + jbase + (ar & 7);
    const char* wrow = (const char*)Wb + (size_t)grow * RS + wv_k * KE + l4 * 16;
    #pragma unroll
    for (int i = 0; i < KB2; ++i) afr[i] = *(const bf16x8*)(wrow + i * 64);
  }

  const int ab = tid >> 3, aj = tid & 7;   // activation mapping (tid < 256)
  const int jb = jbase + aj;
  float bi = 0.f, bff = 0.f, bg = 0.f, bo = 0.f;
  if (tid < 256){
    bi  = b_ih[jb]        + b_hh[jb];
    bff = b_ih[1024 + jb] + b_hh[1024 + jb];
    bg  = b_ih[2048 + jb] + b_hh[2048 + jb];
    bo  = b_ih[3072 + jb] + b_hh[3072 + jb];
  }
  float c = 0.f;
  float* gl = (float*)lds;                 // alias: [2][32][33] f32 gate exchange
  const int brow = wv_b * 16 + l15;
  const int bswz = (brow & 7) << 4;
  const size_t bbase = (size_t)brow * RS;
  const int kofs0 = wv_k * KE + l4 * 16;
  const f32x4 zero = {0.f, 0.f, 0.f, 0.f};

  for (int t = 0; t < 512; ++t){
    // xp prefetch into regs (L0, acc-owning waves) — overlaps the poll
    float xr0 = 0.f, xr1 = 0.f, xr2 = 0.f, xr3 = 0.f;
    if (!L1R && wv_k == 0){
      const unsigned short* xpt = xp + (size_t)t * 131072 + wv_b * 16 + l15;
      int sr = wv_m * 16 + l4 * 4;
      int g0 = ((sr + 0) >> 3) * 1024 + jbase + ((sr + 0) & 7);
      int g1 = ((sr + 1) >> 3) * 1024 + jbase + ((sr + 1) & 7);
      int g2 = ((sr + 2) >> 3) * 1024 + jbase + ((sr + 2) & 7);
      int g3 = ((sr + 3) >> 3) * 1024 + jbase + ((sr + 3) & 7);
      xr0 = bf2f(xpt[(size_t)g0 * 32]);
      xr1 = bf2f(xpt[(size_t)g1 * 32]);
      xr2 = bf2f(xpt[(size_t)g2 * 32]);
      xr3 = bf2f(xpt[(size_t)g3 * 32]);
    }

    // dataflow wait (wave 0 only; sc0sc1 polls; L1 = merged single-RT dual poll)
    if (wv == 0){
      if (L1R) pollwait2(flag_in, t, flag_self, t - 1, lane);
      else     pollwait (flag_in, t - 1, lane);
    }
    __syncthreads();   // A: poll done; prev-step gl reads done (alias WAR guard)

    // stage B into LDS: NORMAL CACHED global_load_lds, pre-swizzled source
    if (!L1R){
      if (t == 0){
        #pragma unroll
        for (int it = 0; it < 8; ++it)
          *(f32x4*)(lds + it * 8192 + tid * 16) = zero;
      } else {
        const char* hp = (const char*)h_self + (size_t)(t - 1) * 65536;
        #pragma unroll
        for (int it = 0; it < 8; ++it){
          int u = it * 8192 + tid * 16;
          int b = u >> 11, kb = u & 2047;
          gld_lds16(hp + (size_t)b * 2048 + (kb ^ ((b & 7) << 4)), lds + u);
        }
      }
    } else {
      const char* hA = (const char*)h_in + (size_t)t * 65536;     // h1[t] -> lower K half
      #pragma unroll
      for (int it = 0; it < 8; ++it){
        int u = it * 8192 + tid * 16;
        int b = u >> 11, kb = u & 2047;
        gld_lds16(hA + (size_t)b * 2048 + (kb ^ ((b & 7) << 4)), lds + (size_t)b * 4096 + kb);
      }
      if (t == 0){
        #pragma unroll
        for (int it = 0; it < 8; ++it){
          int u = it * 8192 + tid * 16;
          int b = u >> 11, kb = u & 2047;
          *(f32x4*)(lds + (size_t)b * 4096 + 2048 + kb) = zero;
        }
      } else {
        const char* hB = (const char*)h_self + (size_t)(t - 1) * 65536;  // h2[t-1] -> upper half
        #pragma unroll
        for (int it = 0; it < 8; ++it){
          int u = it * 8192 + tid * 16;
          int b = u >> 11, kb = u & 2047;
          gld_lds16(hB + (size_t)b * 2048 + (kb ^ ((b & 7) << 4)), lds + (size_t)b * 4096 + 2048 + kb);
        }
      }
    }
    __syncthreads();   // B: staging visible (compiler drains vmcnt/lgkmcnt)

    // MFMA over this wave's K half, 4 independent chains
    f32x4 a0 = zero, a1 = zero, a2 = zero, a3 = zero;
    if (!L1R && wv_k == 0){ a0[0] = xr0; a0[1] = xr1; a0[2] = xr2; a0[3] = xr3; }
    #pragma unroll
    for (int i = 0; i < KB2; i += 4){
      bf16x8 b0 = *(const bf16x8*)(lds + bbase + (((i + 0) * 64 + kofs0) ^ bswz));
      bf16x8 b1 = *(const bf16x8*)(lds + bbase + (((i + 1) * 64 + kofs0) ^ bswz));
      bf16x8 b2 = *(const bf16x8*)(lds + bbase + (((i + 2) * 64 + kofs0) ^ bswz));
      bf16x8 b3 = *(const bf16x8*)(lds + bbase + (((i + 3) * 64 + kofs0) ^ bswz));
      a0 = __builtin_amdgcn_mfma_f32_16x16x32_bf16(afr[i + 0], b0, a0, 0, 0, 0);
      a1 = __builtin_amdgcn_mfma_f32_16x16x32_bf16(afr[i + 1], b1, a1, 0, 0, 0);
      a2 = __builtin_amdgcn_mfma_f32_16x16x32_bf16(afr[i + 2], b2, a2, 0, 0, 0);
      a3 = __builtin_amdgcn_mfma_f32_16x16x32_bf16(afr[i + 3], b3, a3, 0, 0, 0);
    }
    a0 += a1; a2 += a3; a0 += a2;
    __syncthreads();   // C: all LDS B reads done -> safe to write gl (alias)

    // gate exchange (per K-half partials)
    {
      int srow = wv_m * 16 + l4 * 4;
      float* g = gl + wv_k * 1056 + srow * 33 + wv_b * 16 + l15;
      g[0] = a0[0]; g[33] = a0[1]; g[66] = a0[2]; g[99] = a0[3];
    }
    __syncthreads();   // D

    // activation + state update + packed 8B publish (threads 0..255)
    if (tid < 256){
      float gi = gl[aj * 33 + ab]          + gl[1056 + aj * 33 + ab]          + bi;
      float gf = gl[(8 + aj) * 33 + ab]    + gl[1056 + (8 + aj) * 33 + ab]    + bff;
      float gg = gl[(16 + aj) * 33 + ab]   + gl[1056 + (16 + aj) * 33 + ab]   + bg;
      float go = gl[(24 + aj) * 33 + ab]   + gl[1056 + (24 + aj) * 33 + ab]   + bo;
      float i_ = 1.f / (1.f + __expf(-gi));
      float f_ = 1.f / (1.f + __expf(-gf));
      float g_ = 1.f - 2.f / (1.f + __expf(2.f * gg));
      float o_ = 1.f / (1.f + __expf(-go));
      c = f_ * c + i_ * g_;
      float h_ = o_ * (1.f - 2.f / (1.f + __expf(2.f * c)));
      unsigned p = (unsigned)f2bf(h_);
      unsigned w = p | (((unsigned)__shfl_xor((int)p, 1) & 0xFFFFu) << 16);  // units (aj, aj+1)
      unsigned d1 = (unsigned)__shfl_xor((int)w, 2);                          // units (aj+2, aj+3)
      if ((aj & 3) == 0){
        u32x2 W2; W2.x = w; W2.y = d1;
        gstore8_cc((char*)h_self + (size_t)t * 65536 + (size_t)ab * 2048 + (size_t)(jbase + aj) * 2, W2);
      }
    }
    wait_vm0();        // own wave's publish stores retired at LLC
    __syncthreads();   // E: all waves' stores retired; gl reads done
    if (tid == 0)
      __hip_atomic_store(flag_self + jslot, t, __ATOMIC_RELAXED, __HIP_MEMORY_SCOPE_AGENT);
  }
}

__global__ __launch_bounds__(512, 1)
void k_fused(const unsigned short* __restrict__ Whh0b,
             const unsigned short* __restrict__ Wcat1,
             const unsigned short* __restrict__ xp,
             const float* __restrict__ bih0, const float* __restrict__ bhh0,
             const float* __restrict__ bih1, const float* __restrict__ bhh1,
             unsigned short* __restrict__ h1seq, unsigned short* __restrict__ h2seq,
             int* __restrict__ flag0, int* __restrict__ flag1)
{
  __shared__ char lds[131072];
  __threadfence();     // one-time L1/L2 invalidate: clear any stale pre-run lines
  const int bid = blockIdx.x;
  if (bid < 128)
    run_lstm5<0>(Whh0b, xp, bih0, bhh0, h1seq, nullptr, flag0, flag0, bid, lds);
  else
    run_lstm5<1>(Wcat1, nullptr, bih1, bhh1, h2seq, h1seq, flag1, flag0, bid - 128, lds);
}

// ---------------- NT GEMM: C[m][n] = sum_k A[m][k]*B[n][k], K=1024, tile 128x128 ----------------
// mode 1: out f32 [b][t][v] (tb = m: b = tb&31, t = tb>>5, v = n) + bias bp[v]
__global__ __launch_bounds__(256, 2)
void k_gemm(const unsigned short* __restrict__ A,
            const unsigned short* __restrict__ B,
            int Mtiles, void* __restrict__ outp,
            const float* __restrict__ bp, int mode)
{
  __shared__ char As[16384];
  __shared__ char Bs[16384];
  const int tid = threadIdx.x, lane = tid & 63, wv = tid >> 6;
  const int mq = (wv >> 1) * 64, nq = (wv & 1) * 64;
  const int l15 = lane & 15, l4 = (lane >> 4) & 3;
  const int mt = blockIdx.x % Mtiles, nt = blockIdx.x / Mtiles;
  const char* Abase = (const char*)A + (size_t)(mt * 128) * 2048;
  const char* Bbase = (const char*)B + (size_t)(nt * 128) * 2048;
  const f32x4 zero = {0.f, 0.f, 0.f, 0.f};
  f32x4 acc[4][4];
  #pragma unroll
  for (int i = 0; i < 4; ++i)
    #pragma unroll
    for (int j = 0; j < 4; ++j) acc[i][j] = zero;

  for (int kt = 0; kt < 16; ++kt){
    __syncthreads();
    #pragma unroll
    for (int p = 0; p < 4; ++p){
      int o = p * 4096 + tid * 16;
      int row = o >> 7, kb = o & 127;
      gld_lds16(Abase + (size_t)row * 2048 + kt * 128 + (kb ^ ((row & 7) << 4)), As + o);
    }
    #pragma unroll
    for (int p = 0; p < 4; ++p){
      int o = p * 4096 + tid * 16;
      int row = o >> 7, kb = o & 127;
      gld_lds16(Bbase + (size_t)row * 2048 + kt * 128 + (kb ^ ((row & 7) << 4)), Bs + o);
    }
    __syncthreads();
    #pragma unroll
    for (int kk = 0; kk < 2; ++kk){
      bf16x8 af[4], bfr[4];
      #pragma unroll
      for (int i = 0; i < 4; ++i){
        int row = mq + i * 16 + l15;
        int kbyte = kk * 64 + l4 * 16;
        af[i]  = *(const bf16x8*)(As + row * 128 + (kbyte ^ ((row & 7) << 4)));
        int nrow = nq + i * 16 + l15;
        bfr[i] = *(const bf16x8*)(Bs + nrow * 128 + (kbyte ^ ((nrow & 7) << 4)));
      }
      #pragma unroll
      for (int i = 0; i < 4; ++i)
        #pragma unroll
        for (int j = 0; j < 4; ++j)
          acc[i][j] = __builtin_amdgcn_mfma_f32_16x16x32_bf16(af[i], bfr[j], acc[i][j], 0, 0, 0);
    }
  }

  if (mode == 0){
    unsigned short* o16 = (unsigned short*)outp;
    #pragma unroll
    for (int i = 0; i < 4; ++i)
      #pragma unroll
      for (int j = 0; j < 4; ++j){
        int n = nt * 128 + nq + j * 16 + l15;
        int tt = n >> 5, bc = n & 31;
        #pragma unroll
        for (int r = 0; r < 4; ++r){
          int m = mt * 128 + mq + i * 16 + l4 * 4 + r;
          o16[(size_t)tt * 131072 + (size_t)m * 32 + bc] = f2bf(acc[i][j][r]);
        }
      }
  } else {
    float* of = (float*)outp;
    #pragma unroll
    for (int j = 0; j < 4; ++j){
      int v = nt * 128 + nq + j * 16 + l15;
      float bias = bp[v];
      #pragma unroll
      for (int i = 0; i < 4; ++i)
        #pragma unroll
        for (int r = 0; r < 4; ++r){
          int tb = mt * 128 + mq + i * 16 + l4 * 4 + r;
          int tt = tb >> 5, bb2 = tb & 31;
          of[(size_t)bb2 * 2097152 + (size_t)tt * 4096 + v] = acc[i][j][r] + bias;
        }
    }
  }
}

extern "C" void kernel_launch(void* const* d_in, const int* in_sizes, int n_in,
                              void* d_out, int out_size, void* d_ws, size_t ws_size,
                              hipStream_t stream)
{
  const int*   x    = (const int*)  d_in[0];
  const float* Wih0 = (const float*)d_in[1];
  const float* Whh0 = (const float*)d_in[2];
  const float* bih0 = (const float*)d_in[3];
  const float* bhh0 = (const float*)d_in[4];
  const float* Wih1 = (const float*)d_in[5];
  const float* Whh1 = (const float*)d_in[6];
  const float* bih1 = (const float*)d_in[7];
  const float* bhh1 = (const float*)d_in[8];
  const float* Wph  = (const float*)d_in[9];
  const float* bp   = (const float*)d_in[10];

  char* ws = (char*)d_ws;
  int* flag0 = (int*)ws;                      // 128 ints
  int* flag1 = (int*)(ws + 512);              // 128 ints
  unsigned short* Whh0b = (unsigned short*)(ws + 4096);                    // 8MB
  char* regA = ws + 4096 + 8388608;                                        // 32MB region
  unsigned short* Wt0   = (unsigned short*)regA;                           // 32MB (pre-phase)
  unsigned short* Wcat1 = (unsigned short*)regA;                           // 16MB (reuses Wt0)
  unsigned short* WphT  = (unsigned short*)(regA + 16777216);              // 8MB
  unsigned short* h1seq = (unsigned short*)(ws + 4096 + 8388608 + 33554432);            // 32MB
  unsigned short* h2seq = (unsigned short*)(ws + 4096 + 8388608 + 33554432 + 33554432); // 32MB
  unsigned short* xpbuf = (unsigned short*)d_out;  // xp0 scratch inside d_out (rewritten at end)

  hipMemsetAsync(d_ws, 0xFF, 1024, stream);        // flags := -1

  k_transpose_cast<<<16384, 256, 0, stream>>>(Wih0, Wt0, 4096, 4096);      // Wt0[v][r]
  k_gather<<<4096, 256, 0, stream>>>(Wt0, x, xpbuf);                       // xp0 -> d_out
  k_cast<<<4096, 256, 0, stream>>>(Whh0, Whh0b, 4194304);
  k_cast2<<<4096, 256, 0, stream>>>(Wih1, Wcat1, 0);                       // Wcat1[:, 0:1024]
  k_cast2<<<4096, 256, 0, stream>>>(Whh1, Wcat1, 1024);                    // Wcat1[:, 1024:2048]
  k_transpose_cast<<<4096, 256, 0, stream>>>(Wph, WphT, 1024, 4096);       // WphT[v][k]

  k_fused<<<256, 512, 0, stream>>>(Whh0b, Wcat1, xpbuf, bih0, bhh0, bih1, bhh1,
                                   h1seq, h2seq, flag0, flag1);

  k_gemm<<<4096, 256, 0, stream>>>(h2seq, WphT, 128, d_out, bp, 1);        // logits (fp32)
}

// Round 12
// 2385.609 us; speedup vs baseline: 1.4581x; 1.4581x over previous
//
#include <hip/hip_runtime.h>
#include <cstdint>

typedef short bf16x8 __attribute__((ext_vector_type(8)));
typedef float f32x4 __attribute__((ext_vector_type(4)));
typedef unsigned u32x2 __attribute__((ext_vector_type(2)));

__device__ __forceinline__ unsigned short f2bf(float f){
  unsigned u = __float_as_uint(f);
  u = u + 0x7fffu + ((u >> 16) & 1u);      // RNE
  return (unsigned short)(u >> 16);
}
__device__ __forceinline__ float bf2f(unsigned short h){
  return __uint_as_float(((unsigned)h) << 16);
}

__device__ __forceinline__ void gld_lds16(const void* g, void* l){
  __builtin_amdgcn_global_load_lds((const __attribute__((address_space(1))) unsigned*)g,
                                   (__attribute__((address_space(3))) unsigned*)l, 16, 0, 0);
}

// L2-bypassing (LLC-coherent) ops — used ONLY for publish + flag polling
__device__ __forceinline__ void gstore8_cc(void* p, u32x2 v){
  asm volatile("global_store_dwordx2 %0, %1, off sc0 sc1" :: "v"(p), "v"(v) : "memory");
}
__device__ __forceinline__ void wait_vm0(){
  asm volatile("s_waitcnt vmcnt(0)" ::: "memory");
  __builtin_amdgcn_sched_barrier(0);
}

// all 64 flags (int) >= t ; one dword per lane
__device__ __forceinline__ void pollwait64(const int* f, int t, int lane){
  const int* p = f + lane;
  for (;;){
    int v;
    asm volatile("global_load_dword %0, %1, off sc0 sc1\n\ts_waitcnt vmcnt(0)"
                 : "=v"(v) : "v"(p) : "memory");
    if (__all(v >= t)) break;
    __builtin_amdgcn_s_sleep(2);
  }
}

// ---------------- elementwise f32 -> bf16 cast ----------------
__global__ __launch_bounds__(256)
void k_cast(const float* __restrict__ in, unsigned short* __restrict__ out, int n){
  int i = (blockIdx.x * 256 + threadIdx.x) * 4;
  if (i + 3 < n){
    float4 v = *(const float4*)(in + i);
    ushort4 u;
    u.x = f2bf(v.x); u.y = f2bf(v.y); u.z = f2bf(v.z); u.w = f2bf(v.w);
    *(ushort4*)(out + i) = u;
  }
}

// ---------------- cast f32 [4096][1024] into bf16 [4096][2048] at column offset ----------------
__global__ __launch_bounds__(256)
void k_cast2(const float* __restrict__ in, unsigned short* __restrict__ out, int coloff){
  int i = (blockIdx.x * 256 + threadIdx.x) * 4;
  if (i + 3 < 4194304){
    float4 v = *(const float4*)(in + i);
    ushort4 u;
    u.x = f2bf(v.x); u.y = f2bf(v.y); u.z = f2bf(v.z); u.w = f2bf(v.w);
    int r = i >> 10, c = i & 1023;
    *(ushort4*)(out + (size_t)r * 2048 + coloff + c) = u;
  }
}

// ---------------- transpose + cast: in f32 [R][C] -> out bf16 [C][R] ----------------
__global__ __launch_bounds__(256)
void k_transpose_cast(const float* __restrict__ in, unsigned short* __restrict__ out,
                      int R, int C){
  __shared__ float tile[32][33];
  int tpr = C >> 5;
  int r0 = (blockIdx.x / tpr) * 32, c0 = (blockIdx.x % tpr) * 32;
  int lc = threadIdx.x & 31, lr = threadIdx.x >> 5;
  #pragma unroll
  for (int it = 0; it < 4; ++it)
    tile[lr + it*8][lc] = in[(size_t)(r0 + lr + it*8) * C + c0 + lc];
  __syncthreads();
  #pragma unroll
  for (int it = 0; it < 4; ++it){
    int oc = lr + it*8;
    out[(size_t)(c0 + oc) * R + r0 + lc] = f2bf(tile[lc][oc]);
  }
}

// ---------------- embedding gather: xp0[t][r][b] = Wt0[x[b][t]][r] (bf16) ----------------
__global__ __launch_bounds__(256)
void k_gather(const unsigned short* __restrict__ Wt0, const int* __restrict__ x,
              unsigned short* __restrict__ xp){
  __shared__ unsigned short tile[32][520];
  __shared__ int tok[32];
  const int tid = threadIdx.x;
  const int t = blockIdx.x >> 3, rbase = (blockIdx.x & 7) * 512;
  if (tid < 32) tok[tid] = x[tid * 512 + t];
  __syncthreads();
  for (int b = 0; b < 32; ++b){
    unsigned v = *(const unsigned*)(Wt0 + (size_t)tok[b] * 4096 + rbase + tid * 2);
    *(unsigned*)&tile[b][tid * 2] = v;
  }
  __syncthreads();
  #pragma unroll
  for (int i = 0; i < 2; ++i){
    int rl = tid + i * 256;
    unsigned short vals[32];
    #pragma unroll
    for (int b = 0; b < 32; ++b) vals[b] = tile[b][rl];
    char* dst = (char*)xp + ((size_t)t * 131072 + (size_t)(rbase + rl) * 32) * 2;
    #pragma unroll
    for (int q = 0; q < 4; ++q){
      uint4 w;
      w.x = (unsigned)vals[q*8+0] | ((unsigned)vals[q*8+1] << 16);
      w.y = (unsigned)vals[q*8+2] | ((unsigned)vals[q*8+3] << 16);
      w.z = (unsigned)vals[q*8+4] | ((unsigned)vals[q*8+5] << 16);
      w.w = (unsigned)vals[q*8+6] | ((unsigned)vals[q*8+7] << 16);
      *(uint4*)(dst + q * 16) = w;
    }
  }
}

// ---------------- fused persistent 2-layer LSTM, TWO independent batch pipelines ----------------
// 256 blocks x 512 thr, 1 block/CU (forced by 128KB LDS decl). Batch dim split into 2
// independent groups of 16 (LSTM chains couple only within a batch element).
// Per layer per group: 64 blocks x (16 hidden units x 16 batches). Group pipelines share
// nothing: own flag arrays, own h rows. Per-block protocol is byte-equivalent to the R10
// champion: sequential polls (L1: flag_in then flag_self), cached global_load_lds staging
// with swizzle, 5 barriers A-E, sc0sc1 packed publish, relaxed flag store.
// hseq: [t][b(32)][k(1024)] bf16 (groups own disjoint b-rows). xp: [t][r(4096)][b(32)].
template<int L1R>
__device__ __forceinline__ void run_lstm8(
    const unsigned short* __restrict__ Wb,      // bf16 [4096][KE]
    const unsigned short* __restrict__ xp,      // L0 only
    const float* __restrict__ b_ih, const float* __restrict__ b_hh,
    unsigned short* __restrict__ h_self,        // own layer output [512][32][1024]
    const unsigned short* __restrict__ h_in,    // L1: h1seq
    int* __restrict__ flag_self, const int* __restrict__ flag_in,
    int jslot, int gbase, char* lds)
{
  constexpr int KE  = L1R ? 2048 : 1024;   // K elems
  constexpr int RS  = KE * 2;              // row stride bytes (W and LDS tile)
  constexpr int KB2 = KE / 64;             // MFMA k-steps per wave (K split by 2)

  const int tid = threadIdx.x, lane = tid & 63, wv = tid >> 6;
  const int wv_k = wv & 1, wv_m = wv >> 1;           // K half, M-tile (= gate)
  const int l15 = lane & 15, l4 = (lane >> 4) & 3;
  const int jbase = jslot * 16;

  // A fragments in registers: gate wv_m, unit rows jbase..+16, K half wv_k
  bf16x8 afr[KB2];
  {
    const int grow = wv_m * 1024 + jbase + l15;
    const char* wrow = (const char*)Wb + (size_t)grow * RS + wv_k * KE + l4 * 16;
    #pragma unroll
    for (int i = 0; i < KB2; ++i) afr[i] = *(const bf16x8*)(wrow + i * 64);
  }

  const int ab = tid >> 4, aj = tid & 15;  // activation mapping (tid < 256): batch, unit
  const int jb = jbase + aj;
  float bi = 0.f, bff = 0.f, bg = 0.f, bo = 0.f;
  if (tid < 256){
    bi  = b_ih[jb]        + b_hh[jb];
    bff = b_ih[1024 + jb] + b_hh[1024 + jb];
    bg  = b_ih[2048 + jb] + b_hh[2048 + jb];
    bo  = b_ih[3072 + jb] + b_hh[3072 + jb];
  }
  float c = 0.f;
  float* gl = (float*)lds;                 // alias: [2][64][17] f32 gate exchange
  const size_t bbase = (size_t)l15 * RS;   // batch row l15 (16 rows)
  const int bswz = (l15 & 7) << 4;
  const int kofs0 = wv_k * KE + l4 * 16;
  const f32x4 zero = {0.f, 0.f, 0.f, 0.f};

  for (int t = 0; t < 512; ++t){
    // xp prefetch into regs (L0, activation threads) — overlaps the poll
    float xr0 = 0.f, xr1 = 0.f, xr2 = 0.f, xr3 = 0.f;
    if (!L1R && tid < 256){
      const unsigned short* xpt = xp + (size_t)t * 131072 + gbase + ab;
      xr0 = bf2f(xpt[(size_t)jb * 32]);
      xr1 = bf2f(xpt[(size_t)(1024 + jb) * 32]);
      xr2 = bf2f(xpt[(size_t)(2048 + jb) * 32]);
      xr3 = bf2f(xpt[(size_t)(3072 + jb) * 32]);
    }

    // dataflow wait (wave 0 only; sequential polls — champion-proven order)
    if (wv == 0){
      if (L1R){
        pollwait64(flag_in,   t,     lane);   // h1[t] (group) ready
        pollwait64(flag_self, t - 1, lane);   // h2[t-1] (group) ready
      } else {
        pollwait64(flag_in,   t - 1, lane);   // h1[t-1] (group) ready
      }
    }
    __syncthreads();   // A: poll done; prev-step gl reads done (alias WAR guard)

    // stage B into LDS: cached global_load_lds, pre-swizzled source (16 rows = 32KB/region)
    if (!L1R){
      if (t == 0){
        #pragma unroll
        for (int it = 0; it < 4; ++it)
          *(f32x4*)(lds + it * 8192 + tid * 16) = zero;
      } else {
        const char* hp = (const char*)h_self + (size_t)(t - 1) * 65536 + (size_t)gbase * 2048;
        #pragma unroll
        for (int it = 0; it < 4; ++it){
          int u = it * 8192 + tid * 16;
          int b = u >> 11, kb = u & 2047;
          gld_lds16(hp + (size_t)b * 2048 + (kb ^ ((b & 7) << 4)), lds + u);
        }
      }
    } else {
      const char* hA = (const char*)h_in + (size_t)t * 65536 + (size_t)gbase * 2048;  // h1[t] -> lower K half
      #pragma unroll
      for (int it = 0; it < 4; ++it){
        int u = it * 8192 + tid * 16;
        int b = u >> 11, kb = u & 2047;
        gld_lds16(hA + (size_t)b * 2048 + (kb ^ ((b & 7) << 4)), lds + (size_t)b * 4096 + kb);
      }
      if (t == 0){
        #pragma unroll
        for (int it = 0; it < 4; ++it){
          int u = it * 8192 + tid * 16;
          int b = u >> 11, kb = u & 2047;
          *(f32x4*)(lds + (size_t)b * 4096 + 2048 + kb) = zero;
        }
      } else {
        const char* hB = (const char*)h_self + (size_t)(t - 1) * 65536 + (size_t)gbase * 2048; // h2[t-1] -> upper
        #pragma unroll
        for (int it = 0; it < 4; ++it){
          int u = it * 8192 + tid * 16;
          int b = u >> 11, kb = u & 2047;
          gld_lds16(hB + (size_t)b * 2048 + (kb ^ ((b & 7) << 4)), lds + (size_t)b * 4096 + 2048 + kb);
        }
      }
    }
    __syncthreads();   // B: staging visible (compiler drains vmcnt/lgkmcnt)

    // MFMA over this wave's K half, 4 independent chains (k-step parity), one N-tile
    f32x4 a0 = zero, a1 = zero, a2 = zero, a3 = zero;
    #pragma unroll
    for (int i = 0; i < KB2; i += 4){
      bf16x8 b0 = *(const bf16x8*)(lds + bbase + (((i + 0) * 64 + kofs0) ^ bswz));
      bf16x8 b1 = *(const bf16x8*)(lds + bbase + (((i + 1) * 64 + kofs0) ^ bswz));
      bf16x8 b2 = *(const bf16x8*)(lds + bbase + (((i + 2) * 64 + kofs0) ^ bswz));
      bf16x8 b3 = *(const bf16x8*)(lds + bbase + (((i + 3) * 64 + kofs0) ^ bswz));
      a0 = __builtin_amdgcn_mfma_f32_16x16x32_bf16(afr[i + 0], b0, a0, 0, 0, 0);
      a1 = __builtin_amdgcn_mfma_f32_16x16x32_bf16(afr[i + 1], b1, a1, 0, 0, 0);
      a2 = __builtin_amdgcn_mfma_f32_16x16x32_bf16(afr[i + 2], b2, a2, 0, 0, 0);
      a3 = __builtin_amdgcn_mfma_f32_16x16x32_bf16(afr[i + 3], b3, a3, 0, 0, 0);
    }
    a0 += a1; a2 += a3; a0 += a2;
    __syncthreads();   // C: all LDS B reads done -> safe to write gl (alias)

    // gate exchange (per K-half partials): gl[kh][srow 64][col 17]
    {
      int srow = wv_m * 16 + l4 * 4;
      float* g = gl + wv_k * 1088 + srow * 17 + l15;
      g[0] = a0[0]; g[17] = a0[1]; g[34] = a0[2]; g[51] = a0[3];
    }
    __syncthreads();   // D

    // activation + state update + packed 8B publish (threads 0..255)
    if (tid < 256){
      float gi = gl[aj * 17 + ab]        + gl[1088 + aj * 17 + ab]        + xr0 + bi;
      float gf = gl[(16 + aj) * 17 + ab] + gl[1088 + (16 + aj) * 17 + ab] + xr1 + bff;
      float gg = gl[(32 + aj) * 17 + ab] + gl[1088 + (32 + aj) * 17 + ab] + xr2 + bg;
      float go = gl[(48 + aj) * 17 + ab] + gl[1088 + (48 + aj) * 17 + ab] + xr3 + bo;
      float i_ = 1.f / (1.f + __expf(-gi));
      float f_ = 1.f / (1.f + __expf(-gf));
      float g_ = 1.f - 2.f / (1.f + __expf(2.f * gg));
      float o_ = 1.f / (1.f + __expf(-go));
      c = f_ * c + i_ * g_;
      float h_ = o_ * (1.f - 2.f / (1.f + __expf(2.f * c)));
      unsigned p = (unsigned)f2bf(h_);
      unsigned w = p | (((unsigned)__shfl_xor((int)p, 1) & 0xFFFFu) << 16);  // units (aj, aj+1)
      unsigned d1 = (unsigned)__shfl_xor((int)w, 2);                          // units (aj+2, aj+3)
      if ((aj & 3) == 0){
        u32x2 W2; W2.x = w; W2.y = d1;
        gstore8_cc((char*)h_self + (size_t)t * 65536 + (size_t)(gbase + ab) * 2048
                   + (size_t)(jbase + aj) * 2, W2);
      }
    }
    wait_vm0();        // own wave's publish stores retired at LLC
    __syncthreads();   // E: all waves' stores retired; gl reads done
    if (tid == 0)
      __hip_atomic_store(flag_self + jslot, t, __ATOMIC_RELAXED, __HIP_MEMORY_SCOPE_AGENT);
  }
}

__global__ __launch_bounds__(512, 1)
void k_fused(const unsigned short* __restrict__ Whh0b,
             const unsigned short* __restrict__ Wcat1,
             const unsigned short* __restrict__ xp,
             const float* __restrict__ bih0, const float* __restrict__ bhh0,
             const float* __restrict__ bih1, const float* __restrict__ bhh1,
             unsigned short* __restrict__ h1seq, unsigned short* __restrict__ h2seq,
             int* __restrict__ flags)
{
  __shared__ char lds[131072];   // forces 1 block/CU (tile uses <=64KB; gl aliases start)
  __threadfence();     // one-time L1/L2 invalidate: clear any stale pre-run lines
  const int bid = blockIdx.x;
  const int layer = bid >> 7;          // 0 / 1
  const int lbid  = bid & 127;
  const int grp   = lbid >> 6;         // batch group 0 / 1
  const int jslot = lbid & 63;
  const int gbase = grp * 16;
  int* f0 = flags + grp * 128;         // layer-0 flags for this group (64 ints, 512B apart)
  int* f1 = flags + 256 + grp * 128;   // layer-1 flags for this group
  if (layer == 0)
    run_lstm8<0>(Whh0b, xp, bih0, bhh0, h1seq, nullptr, f0, f0, jslot, gbase, lds);
  else
    run_lstm8<1>(Wcat1, nullptr, bih1, bhh1, h2seq, h1seq, f1, f0, jslot, gbase, lds);
}

// ---------------- NT GEMM: C[m][n] = sum_k A[m][k]*B[n][k], K=1024, tile 128x128 ----------------
// mode 1: out f32 [b][t][v] (tb = m: b = tb&31, t = tb>>5, v = n) + bias bp[v]
__global__ __launch_bounds__(256, 2)
void k_gemm(const unsigned short* __restrict__ A,
            const unsigned short* __restrict__ B,
            int Mtiles, void* __restrict__ outp,
            const float* __restrict__ bp, int mode)
{
  __shared__ char As[16384];
  __shared__ char Bs[16384];
  const int tid = threadIdx.x, lane = tid & 63, wv = tid >> 6;
  const int mq = (wv >> 1) * 64, nq = (wv & 1) * 64;
  const int l15 = lane & 15, l4 = (lane >> 4) & 3;
  const int mt = blockIdx.x % Mtiles, nt = blockIdx.x / Mtiles;
  const char* Abase = (const char*)A + (size_t)(mt * 128) * 2048;
  const char* Bbase = (const char*)B + (size_t)(nt * 128) * 2048;
  const f32x4 zero = {0.f, 0.f, 0.f, 0.f};
  f32x4 acc[4][4];
  #pragma unroll
  for (int i = 0; i < 4; ++i)
    #pragma unroll
    for (int j = 0; j < 4; ++j) acc[i][j] = zero;

  for (int kt = 0; kt < 16; ++kt){
    __syncthreads();
    #pragma unroll
    for (int p = 0; p < 4; ++p){
      int o = p * 4096 + tid * 16;
      int row = o >> 7, kb = o & 127;
      gld_lds16(Abase + (size_t)row * 2048 + kt * 128 + (kb ^ ((row & 7) << 4)), As + o);
    }
    #pragma unroll
    for (int p = 0; p < 4; ++p){
      int o = p * 4096 + tid * 16;
      int row = o >> 7, kb = o & 127;
      gld_lds16(Bbase + (size_t)row * 2048 + kt * 128 + (kb ^ ((row & 7) << 4)), Bs + o);
    }
    __syncthreads();
    #pragma unroll
    for (int kk = 0; kk < 2; ++kk){
      bf16x8 af[4], bfr[4];
      #pragma unroll
      for (int i = 0; i < 4; ++i){
        int row = mq + i * 16 + l15;
        int kbyte = kk * 64 + l4 * 16;
        af[i]  = *(const bf16x8*)(As + row * 128 + (kbyte ^ ((row & 7) << 4)));
        int nrow = nq + i * 16 + l15;
        bfr[i] = *(const bf16x8*)(Bs + nrow * 128 + (kbyte ^ ((nrow & 7) << 4)));
      }
      #pragma unroll
      for (int i = 0; i < 4; ++i)
        #pragma unroll
        for (int j = 0; j < 4; ++j)
          acc[i][j] = __builtin_amdgcn_mfma_f32_16x16x32_bf16(af[i], bfr[j], acc[i][j], 0, 0, 0);
    }
  }

  if (mode == 0){
    unsigned short* o16 = (unsigned short*)outp;
    #pragma unroll
    for (int i = 0; i < 4; ++i)
      #pragma unroll
      for (int j = 0; j < 4; ++j){
        int n = nt * 128 + nq + j * 16 + l15;
        int tt = n >> 5, bc = n & 31;
        #pragma unroll
        for (int r = 0; r < 4; ++r){
          int m = mt * 128 + mq + i * 16 + l4 * 4 + r;
          o16[(size_t)tt * 131072 + (size_t)m * 32 + bc] = f2bf(acc[i][j][r]);
        }
      }
  } else {
    float* of = (float*)outp;
    #pragma unroll
    for (int j = 0; j < 4; ++j){
      int v = nt * 128 + nq + j * 16 + l15;
      float bias = bp[v];
      #pragma unroll
      for (int i = 0; i < 4; ++i)
        #pragma unroll
        for (int r = 0; r < 4; ++r){
          int tb = mt * 128 + mq + i * 16 + l4 * 4 + r;
          int tt = tb >> 5, bb2 = tb & 31;
          of[(size_t)bb2 * 2097152 + (size_t)tt * 4096 + v] = acc[i][j][r] + bias;
        }
    }
  }
}

extern "C" void kernel_launch(void* const* d_in, const int* in_sizes, int n_in,
                              void* d_out, int out_size, void* d_ws, size_t ws_size,
                              hipStream_t stream)
{
  const int*   x    = (const int*)  d_in[0];
  const float* Wih0 = (const float*)d_in[1];
  const float* Whh0 = (const float*)d_in[2];
  const float* bih0 = (const float*)d_in[3];
  const float* bhh0 = (const float*)d_in[4];
  const float* Wih1 = (const float*)d_in[5];
  const float* Whh1 = (const float*)d_in[6];
  const float* bih1 = (const float*)d_in[7];
  const float* bhh1 = (const float*)d_in[8];
  const float* Wph  = (const float*)d_in[9];
  const float* bp   = (const float*)d_in[10];

  char* ws = (char*)d_ws;
  int* flags = (int*)ws;                      // 4 x 64 ints at 512B spacing (2KB total)
  unsigned short* Whh0b = (unsigned short*)(ws + 4096);                    // 8MB
  char* regA = ws + 4096 + 8388608;                                        // 32MB region
  unsigned short* Wt0   = (unsigned short*)regA;                           // 32MB (pre-phase)
  unsigned short* Wcat1 = (unsigned short*)regA;                           // 16MB (reuses Wt0)
  unsigned short* WphT  = (unsigned short*)(regA + 16777216);              // 8MB
  unsigned short* h1seq = (unsigned short*)(ws + 4096 + 8388608 + 33554432);            // 32MB
  unsigned short* h2seq = (unsigned short*)(ws + 4096 + 8388608 + 33554432 + 33554432); // 32MB
  unsigned short* xpbuf = (unsigned short*)d_out;  // xp0 scratch inside d_out (rewritten at end)

  hipMemsetAsync(d_ws, 0xFF, 2048, stream);        // all flag arrays := -1

  k_transpose_cast<<<16384, 256, 0, stream>>>(Wih0, Wt0, 4096, 4096);      // Wt0[v][r]
  k_gather<<<4096, 256, 0, stream>>>(Wt0, x, xpbuf);                       // xp0 -> d_out
  k_cast<<<4096, 256, 0, stream>>>(Whh0, Whh0b, 4194304);
  k_cast2<<<4096, 256, 0, stream>>>(Wih1, Wcat1, 0);                       // Wcat1[:, 0:1024]
  k_cast2<<<4096, 256, 0, stream>>>(Whh1, Wcat1, 1024);                    // Wcat1[:, 1024:2048]
  k_transpose_cast<<<4096, 256, 0, stream>>>(Wph, WphT, 1024, 4096);       // WphT[v][k]

  k_fused<<<256, 512, 0, stream>>>(Whh0b, Wcat1, xpbuf, bih0, bhh0, bih1, bhh1,
                                   h1seq, h2seq, flags);

  k_gemm<<<4096, 256, 0, stream>>>(h2seq, WphT, 128, d_out, bp, 1);        // logits (fp32)
}

// Round 13
// 2260.939 us; speedup vs baseline: 1.5385x; 1.0551x over previous
//
#include <hip/hip_runtime.h>
#include <cstdint>

typedef short bf16x8 __attribute__((ext_vector_type(8)));
typedef float f32x4 __attribute__((ext_vector_type(4)));
typedef unsigned u32x2 __attribute__((ext_vector_type(2)));

__device__ __forceinline__ unsigned short f2bf(float f){
  unsigned u = __float_as_uint(f);
  u = u + 0x7fffu + ((u >> 16) & 1u);      // RNE
  return (unsigned short)(u >> 16);
}
__device__ __forceinline__ float bf2f(unsigned short h){
  return __uint_as_float(((unsigned)h) << 16);
}

__device__ __forceinline__ void gld_lds16(const void* g, void* l){
  __builtin_amdgcn_global_load_lds((const __attribute__((address_space(1))) unsigned*)g,
                                   (__attribute__((address_space(3))) unsigned*)l, 16, 0, 0);
}

// L2-bypassing (LLC-coherent) ops — used ONLY for publish + flag polling
__device__ __forceinline__ void gstore8_cc(void* p, u32x2 v){
  asm volatile("global_store_dwordx2 %0, %1, off sc0 sc1" :: "v"(p), "v"(v) : "memory");
}
__device__ __forceinline__ void wait_vm0(){
  asm volatile("s_waitcnt vmcnt(0)" ::: "memory");
  __builtin_amdgcn_sched_barrier(0);
}

// all 64 flags (int) >= t ; one dword per lane
__device__ __forceinline__ void pollwait64(const int* f, int t, int lane){
  const int* p = f + lane;
  for (;;){
    int v;
    asm volatile("global_load_dword %0, %1, off sc0 sc1\n\ts_waitcnt vmcnt(0)"
                 : "=v"(v) : "v"(p) : "memory");
    if (__all(v >= t)) break;
    __builtin_amdgcn_s_sleep(2);
  }
}

// ---------------- elementwise f32 -> bf16 cast ----------------
__global__ __launch_bounds__(256)
void k_cast(const float* __restrict__ in, unsigned short* __restrict__ out, int n){
  int i = (blockIdx.x * 256 + threadIdx.x) * 4;
  if (i + 3 < n){
    float4 v = *(const float4*)(in + i);
    ushort4 u;
    u.x = f2bf(v.x); u.y = f2bf(v.y); u.z = f2bf(v.z); u.w = f2bf(v.w);
    *(ushort4*)(out + i) = u;
  }
}

// ---------------- cast f32 [4096][1024] into bf16 [4096][2048] at column offset ----------------
__global__ __launch_bounds__(256)
void k_cast2(const float* __restrict__ in, unsigned short* __restrict__ out, int coloff){
  int i = (blockIdx.x * 256 + threadIdx.x) * 4;
  if (i + 3 < 4194304){
    float4 v = *(const float4*)(in + i);
    ushort4 u;
    u.x = f2bf(v.x); u.y = f2bf(v.y); u.z = f2bf(v.z); u.w = f2bf(v.w);
    int r = i >> 10, c = i & 1023;
    *(ushort4*)(out + (size_t)r * 2048 + coloff + c) = u;
  }
}

// ---------------- transpose + cast: in f32 [R][C] -> out bf16 [C][R] ----------------
__global__ __launch_bounds__(256)
void k_transpose_cast(const float* __restrict__ in, unsigned short* __restrict__ out,
                      int R, int C){
  __shared__ float tile[32][33];
  int tpr = C >> 5;
  int r0 = (blockIdx.x / tpr) * 32, c0 = (blockIdx.x % tpr) * 32;
  int lc = threadIdx.x & 31, lr = threadIdx.x >> 5;
  #pragma unroll
  for (int it = 0; it < 4; ++it)
    tile[lr + it*8][lc] = in[(size_t)(r0 + lr + it*8) * C + c0 + lc];
  __syncthreads();
  #pragma unroll
  for (int it = 0; it < 4; ++it){
    int oc = lr + it*8;
    out[(size_t)(c0 + oc) * R + r0 + lc] = f2bf(tile[lc][oc]);
  }
}

// ---------------- embedding gather: xp0[t][r][b] = Wt0[x[b][t]][r] (bf16) ----------------
__global__ __launch_bounds__(256)
void k_gather(const unsigned short* __restrict__ Wt0, const int* __restrict__ x,
              unsigned short* __restrict__ xp){
  __shared__ unsigned short tile[32][520];
  __shared__ int tok[32];
  const int tid = threadIdx.x;
  const int t = blockIdx.x >> 3, rbase = (blockIdx.x & 7) * 512;
  if (tid < 32) tok[tid] = x[tid * 512 + t];
  __syncthreads();
  for (int b = 0; b < 32; ++b){
    unsigned v = *(const unsigned*)(Wt0 + (size_t)tok[b] * 4096 + rbase + tid * 2);
    *(unsigned*)&tile[b][tid * 2] = v;
  }
  __syncthreads();
  #pragma unroll
  for (int i = 0; i < 2; ++i){
    int rl = tid + i * 256;
    unsigned short vals[32];
    #pragma unroll
    for (int b = 0; b < 32; ++b) vals[b] = tile[b][rl];
    char* dst = (char*)xp + ((size_t)t * 131072 + (size_t)(rbase + rl) * 32) * 2;
    #pragma unroll
    for (int q = 0; q < 4; ++q){
      uint4 w;
      w.x = (unsigned)vals[q*8+0] | ((unsigned)vals[q*8+1] << 16);
      w.y = (unsigned)vals[q*8+2] | ((unsigned)vals[q*8+3] << 16);
      w.z = (unsigned)vals[q*8+4] | ((unsigned)vals[q*8+5] << 16);
      w.w = (unsigned)vals[q*8+6] | ((unsigned)vals[q*8+7] << 16);
      *(uint4*)(dst + q * 16) = w;
    }
  }
}

// ---------------- fused persistent 2-layer LSTM, TWO independent batch pipelines ----------------
// 256 blocks x 512 thr, 1 block/CU. Batch dim split into 2 independent groups of 16.
// Per layer per group: 64 blocks x (16 hidden units x 16 batches). Per-block protocol is
// byte-identical to the R12 champion. SINGLE CHANGE vs R12: blockIdx decode remapped so
// each (layer, group) team of 64 blocks lands on its own 2 XCDs under the round-robin
// xcd = blockIdx % 8 dispatch heuristic (h-broadcast LLC->L2 re-fetch 8 XCDs -> 2-4).
// Pure permutation: correctness independent of actual dispatch mapping.
template<int L1R>
__device__ __forceinline__ void run_lstm8(
    const unsigned short* __restrict__ Wb,      // bf16 [4096][KE]
    const unsigned short* __restrict__ xp,      // L0 only
    const float* __restrict__ b_ih, const float* __restrict__ b_hh,
    unsigned short* __restrict__ h_self,        // own layer output [512][32][1024]
    const unsigned short* __restrict__ h_in,    // L1: h1seq
    int* __restrict__ flag_self, const int* __restrict__ flag_in,
    int jslot, int gbase, char* lds)
{
  constexpr int KE  = L1R ? 2048 : 1024;   // K elems
  constexpr int RS  = KE * 2;              // row stride bytes (W and LDS tile)
  constexpr int KB2 = KE / 64;             // MFMA k-steps per wave (K split by 2)

  const int tid = threadIdx.x, lane = tid & 63, wv = tid >> 6;
  const int wv_k = wv & 1, wv_m = wv >> 1;           // K half, M-tile (= gate)
  const int l15 = lane & 15, l4 = (lane >> 4) & 3;
  const int jbase = jslot * 16;

  // A fragments in registers: gate wv_m, unit rows jbase..+16, K half wv_k
  bf16x8 afr[KB2];
  {
    const int grow = wv_m * 1024 + jbase + l15;
    const char* wrow = (const char*)Wb + (size_t)grow * RS + wv_k * KE + l4 * 16;
    #pragma unroll
    for (int i = 0; i < KB2; ++i) afr[i] = *(const bf16x8*)(wrow + i * 64);
  }

  const int ab = tid >> 4, aj = tid & 15;  // activation mapping (tid < 256): batch, unit
  const int jb = jbase + aj;
  float bi = 0.f, bff = 0.f, bg = 0.f, bo = 0.f;
  if (tid < 256){
    bi  = b_ih[jb]        + b_hh[jb];
    bff = b_ih[1024 + jb] + b_hh[1024 + jb];
    bg  = b_ih[2048 + jb] + b_hh[2048 + jb];
    bo  = b_ih[3072 + jb] + b_hh[3072 + jb];
  }
  float c = 0.f;
  float* gl = (float*)lds;                 // alias: [2][64][17] f32 gate exchange
  const size_t bbase = (size_t)l15 * RS;   // batch row l15 (16 rows)
  const int bswz = (l15 & 7) << 4;
  const int kofs0 = wv_k * KE + l4 * 16;
  const f32x4 zero = {0.f, 0.f, 0.f, 0.f};

  for (int t = 0; t < 512; ++t){
    // xp prefetch into regs (L0, activation threads) — overlaps the poll
    float xr0 = 0.f, xr1 = 0.f, xr2 = 0.f, xr3 = 0.f;
    if (!L1R && tid < 256){
      const unsigned short* xpt = xp + (size_t)t * 131072 + gbase + ab;
      xr0 = bf2f(xpt[(size_t)jb * 32]);
      xr1 = bf2f(xpt[(size_t)(1024 + jb) * 32]);
      xr2 = bf2f(xpt[(size_t)(2048 + jb) * 32]);
      xr3 = bf2f(xpt[(size_t)(3072 + jb) * 32]);
    }

    // dataflow wait (wave 0 only; sequential polls — champion-proven order)
    if (wv == 0){
      if (L1R){
        pollwait64(flag_in,   t,     lane);   // h1[t] (group) ready
        pollwait64(flag_self, t - 1, lane);   // h2[t-1] (group) ready
      } else {
        pollwait64(flag_in,   t - 1, lane);   // h1[t-1] (group) ready
      }
    }
    __syncthreads();   // A: poll done; prev-step gl reads done (alias WAR guard)

    // stage B into LDS: cached global_load_lds, pre-swizzled source (16 rows = 32KB/region)
    if (!L1R){
      if (t == 0){
        #pragma unroll
        for (int it = 0; it < 4; ++it)
          *(f32x4*)(lds + it * 8192 + tid * 16) = zero;
      } else {
        const char* hp = (const char*)h_self + (size_t)(t - 1) * 65536 + (size_t)gbase * 2048;
        #pragma unroll
        for (int it = 0; it < 4; ++it){
          int u = it * 8192 + tid * 16;
          int b = u >> 11, kb = u & 2047;
          gld_lds16(hp + (size_t)b * 2048 + (kb ^ ((b & 7) << 4)), lds + u);
        }
      }
    } else {
      const char* hA = (const char*)h_in + (size_t)t * 65536 + (size_t)gbase * 2048;  // h1[t] -> lower K half
      #pragma unroll
      for (int it = 0; it < 4; ++it){
        int u = it * 8192 + tid * 16;
        int b = u >> 11, kb = u & 2047;
        gld_lds16(hA + (size_t)b * 2048 + (kb ^ ((b & 7) << 4)), lds + (size_t)b * 4096 + kb);
      }
      if (t == 0){
        #pragma unroll
        for (int it = 0; it < 4; ++it){
          int u = it * 8192 + tid * 16;
          int b = u >> 11, kb = u & 2047;
          *(f32x4*)(lds + (size_t)b * 4096 + 2048 + kb) = zero;
        }
      } else {
        const char* hB = (const char*)h_self + (size_t)(t - 1) * 65536 + (size_t)gbase * 2048; // h2[t-1] -> upper
        #pragma unroll
        for (int it = 0; it < 4; ++it){
          int u = it * 8192 + tid * 16;
          int b = u >> 11, kb = u & 2047;
          gld_lds16(hB + (size_t)b * 2048 + (kb ^ ((b & 7) << 4)), lds + (size_t)b * 4096 + 2048 + kb);
        }
      }
    }
    __syncthreads();   // B: staging visible (compiler drains vmcnt/lgkmcnt)

    // MFMA over this wave's K half, 4 independent chains (k-step parity), one N-tile
    f32x4 a0 = zero, a1 = zero, a2 = zero, a3 = zero;
    #pragma unroll
    for (int i = 0; i < KB2; i += 4){
      bf16x8 b0 = *(const bf16x8*)(lds + bbase + (((i + 0) * 64 + kofs0) ^ bswz));
      bf16x8 b1 = *(const bf16x8*)(lds + bbase + (((i + 1) * 64 + kofs0) ^ bswz));
      bf16x8 b2 = *(const bf16x8*)(lds + bbase + (((i + 2) * 64 + kofs0) ^ bswz));
      bf16x8 b3 = *(const bf16x8*)(lds + bbase + (((i + 3) * 64 + kofs0) ^ bswz));
      a0 = __builtin_amdgcn_mfma_f32_16x16x32_bf16(afr[i + 0], b0, a0, 0, 0, 0);
      a1 = __builtin_amdgcn_mfma_f32_16x16x32_bf16(afr[i + 1], b1, a1, 0, 0, 0);
      a2 = __builtin_amdgcn_mfma_f32_16x16x32_bf16(afr[i + 2], b2, a2, 0, 0, 0);
      a3 = __builtin_amdgcn_mfma_f32_16x16x32_bf16(afr[i + 3], b3, a3, 0, 0, 0);
    }
    a0 += a1; a2 += a3; a0 += a2;
    __syncthreads();   // C: all LDS B reads done -> safe to write gl (alias)

    // gate exchange (per K-half partials): gl[kh][srow 64][col 17]
    {
      int srow = wv_m * 16 + l4 * 4;
      float* g = gl + wv_k * 1088 + srow * 17 + l15;
      g[0] = a0[0]; g[17] = a0[1]; g[34] = a0[2]; g[51] = a0[3];
    }
    __syncthreads();   // D

    // activation + state update + packed 8B publish (threads 0..255)
    if (tid < 256){
      float gi = gl[aj * 17 + ab]        + gl[1088 + aj * 17 + ab]        + xr0 + bi;
      float gf = gl[(16 + aj) * 17 + ab] + gl[1088 + (16 + aj) * 17 + ab] + xr1 + bff;
      float gg = gl[(32 + aj) * 17 + ab] + gl[1088 + (32 + aj) * 17 + ab] + xr2 + bg;
      float go = gl[(48 + aj) * 17 + ab] + gl[1088 + (48 + aj) * 17 + ab] + xr3 + bo;
      float i_ = 1.f / (1.f + __expf(-gi));
      float f_ = 1.f / (1.f + __expf(-gf));
      float g_ = 1.f - 2.f / (1.f + __expf(2.f * gg));
      float o_ = 1.f / (1.f + __expf(-go));
      c = f_ * c + i_ * g_;
      float h_ = o_ * (1.f - 2.f / (1.f + __expf(2.f * c)));
      unsigned p = (unsigned)f2bf(h_);
      unsigned w = p | (((unsigned)__shfl_xor((int)p, 1) & 0xFFFFu) << 16);  // units (aj, aj+1)
      unsigned d1 = (unsigned)__shfl_xor((int)w, 2);                          // units (aj+2, aj+3)
      if ((aj & 3) == 0){
        u32x2 W2; W2.x = w; W2.y = d1;
        gstore8_cc((char*)h_self + (size_t)t * 65536 + (size_t)(gbase + ab) * 2048
                   + (size_t)(jbase + aj) * 2, W2);
      }
    }
    wait_vm0();        // own wave's publish stores retired at LLC
    __syncthreads();   // E: all waves' stores retired; gl reads done
    if (tid == 0)
      __hip_atomic_store(flag_self + jslot, t, __ATOMIC_RELAXED, __HIP_MEMORY_SCOPE_AGENT);
  }
}

__global__ __launch_bounds__(512, 1)
void k_fused(const unsigned short* __restrict__ Whh0b,
             const unsigned short* __restrict__ Wcat1,
             const unsigned short* __restrict__ xp,
             const float* __restrict__ bih0, const float* __restrict__ bhh0,
             const float* __restrict__ bih1, const float* __restrict__ bhh1,
             unsigned short* __restrict__ h1seq, unsigned short* __restrict__ h2seq,
             int* __restrict__ flags)
{
  __shared__ char lds[131072];   // forces 1 block/CU (tile uses <=64KB; gl aliases start)
  __threadfence();     // one-time L1/L2 invalidate: clear any stale pre-run lines
  // XCD-locality decode (assumes round-robin xcd = blockIdx % 8):
  //   bid%8 in {0,1} -> (L0,g0) on XCDs 0,1 ; {2,3} -> (L1,g0) ; {4,5} -> (L0,g1) ; {6,7} -> (L1,g1)
  const int bid = blockIdx.x;
  const int grp   = (bid >> 2) & 1;
  const int layer = (bid >> 1) & 1;
  const int jslot = ((bid >> 3) << 1) | (bid & 1);   // 0..63 within team
  const int gbase = grp * 16;
  int* f0 = flags + grp * 128;         // layer-0 flags for this group (64 ints)
  int* f1 = flags + 256 + grp * 128;   // layer-1 flags for this group
  if (layer == 0)
    run_lstm8<0>(Whh0b, xp, bih0, bhh0, h1seq, nullptr, f0, f0, jslot, gbase, lds);
  else
    run_lstm8<1>(Wcat1, nullptr, bih1, bhh1, h2seq, h1seq, f1, f0, jslot, gbase, lds);
}

// ---------------- NT GEMM: C[m][n] = sum_k A[m][k]*B[n][k], K=1024, tile 128x128 ----------------
// mode 1: out f32 [b][t][v] (tb = m: b = tb&31, t = tb>>5, v = n) + bias bp[v]
__global__ __launch_bounds__(256, 2)
void k_gemm(const unsigned short* __restrict__ A,
            const unsigned short* __restrict__ B,
            int Mtiles, void* __restrict__ outp,
            const float* __restrict__ bp, int mode)
{
  __shared__ char As[16384];
  __shared__ char Bs[16384];
  const int tid = threadIdx.x, lane = tid & 63, wv = tid >> 6;
  const int mq = (wv >> 1) * 64, nq = (wv & 1) * 64;
  const int l15 = lane & 15, l4 = (lane >> 4) & 3;
  const int mt = blockIdx.x % Mtiles, nt = blockIdx.x / Mtiles;
  const char* Abase = (const char*)A + (size_t)(mt * 128) * 2048;
  const char* Bbase = (const char*)B + (size_t)(nt * 128) * 2048;
  const f32x4 zero = {0.f, 0.f, 0.f, 0.f};
  f32x4 acc[4][4];
  #pragma unroll
  for (int i = 0; i < 4; ++i)
    #pragma unroll
    for (int j = 0; j < 4; ++j) acc[i][j] = zero;

  for (int kt = 0; kt < 16; ++kt){
    __syncthreads();
    #pragma unroll
    for (int p = 0; p < 4; ++p){
      int o = p * 4096 + tid * 16;
      int row = o >> 7, kb = o & 127;
      gld_lds16(Abase + (size_t)row * 2048 + kt * 128 + (kb ^ ((row & 7) << 4)), As + o);
    }
    #pragma unroll
    for (int p = 0; p < 4; ++p){
      int o = p * 4096 + tid * 16;
      int row = o >> 7, kb = o & 127;
      gld_lds16(Bbase + (size_t)row * 2048 + kt * 128 + (kb ^ ((row & 7) << 4)), Bs + o);
    }
    __syncthreads();
    #pragma unroll
    for (int kk = 0; kk < 2; ++kk){
      bf16x8 af[4], bfr[4];
      #pragma unroll
      for (int i = 0; i < 4; ++i){
        int row = mq + i * 16 + l15;
        int kbyte = kk * 64 + l4 * 16;
        af[i]  = *(const bf16x8*)(As + row * 128 + (kbyte ^ ((row & 7) << 4)));
        int nrow = nq + i * 16 + l15;
        bfr[i] = *(const bf16x8*)(Bs + nrow * 128 + (kbyte ^ ((nrow & 7) << 4)));
      }
      #pragma unroll
      for (int i = 0; i < 4; ++i)
        #pragma unroll
        for (int j = 0; j < 4; ++j)
          acc[i][j] = __builtin_amdgcn_mfma_f32_16x16x32_bf16(af[i], bfr[j], acc[i][j], 0, 0, 0);
    }
  }

  if (mode == 0){
    unsigned short* o16 = (unsigned short*)outp;
    #pragma unroll
    for (int i = 0; i < 4; ++i)
      #pragma unroll
      for (int j = 0; j < 4; ++j){
        int n = nt * 128 + nq + j * 16 + l15;
        int tt = n >> 5, bc = n & 31;
        #pragma unroll
        for (int r = 0; r < 4; ++r){
          int m = mt * 128 + mq + i * 16 + l4 * 4 + r;
          o16[(size_t)tt * 131072 + (size_t)m * 32 + bc] = f2bf(acc[i][j][r]);
        }
      }
  } else {
    float* of = (float*)outp;
    #pragma unroll
    for (int j = 0; j < 4; ++j){
      int v = nt * 128 + nq + j * 16 + l15;
      float bias = bp[v];
      #pragma unroll
      for (int i = 0; i < 4; ++i)
        #pragma unroll
        for (int r = 0; r < 4; ++r){
          int tb = mt * 128 + mq + i * 16 + l4 * 4 + r;
          int tt = tb >> 5, bb2 = tb & 31;
          of[(size_t)bb2 * 2097152 + (size_t)tt * 4096 + v] = acc[i][j][r] + bias;
        }
    }
  }
}

extern "C" void kernel_launch(void* const* d_in, const int* in_sizes, int n_in,
                              void* d_out, int out_size, void* d_ws, size_t ws_size,
                              hipStream_t stream)
{
  const int*   x    = (const int*)  d_in[0];
  const float* Wih0 = (const float*)d_in[1];
  const float* Whh0 = (const float*)d_in[2];
  const float* bih0 = (const float*)d_in[3];
  const float* bhh0 = (const float*)d_in[4];
  const float* Wih1 = (const float*)d_in[5];
  const float* Whh1 = (const float*)d_in[6];
  const float* bih1 = (const float*)d_in[7];
  const float* bhh1 = (const float*)d_in[8];
  const float* Wph  = (const float*)d_in[9];
  const float* bp   = (const float*)d_in[10];

  char* ws = (char*)d_ws;
  int* flags = (int*)ws;                      // 4 x 64 ints at 512B spacing (2KB total)
  unsigned short* Whh0b = (unsigned short*)(ws + 4096);                    // 8MB
  char* regA = ws + 4096 + 8388608;                                        // 32MB region
  unsigned short* Wt0   = (unsigned short*)regA;                           // 32MB (pre-phase)
  unsigned short* Wcat1 = (unsigned short*)regA;                           // 16MB (reuses Wt0)
  unsigned short* WphT  = (unsigned short*)(regA + 16777216);              // 8MB
  unsigned short* h1seq = (unsigned short*)(ws + 4096 + 8388608 + 33554432);            // 32MB
  unsigned short* h2seq = (unsigned short*)(ws + 4096 + 8388608 + 33554432 + 33554432); // 32MB
  unsigned short* xpbuf = (unsigned short*)d_out;  // xp0 scratch inside d_out (rewritten at end)

  hipMemsetAsync(d_ws, 0xFF, 2048, stream);        // all flag arrays := -1

  k_transpose_cast<<<16384, 256, 0, stream>>>(Wih0, Wt0, 4096, 4096);      // Wt0[v][r]
  k_gather<<<4096, 256, 0, stream>>>(Wt0, x, xpbuf);                       // xp0 -> d_out
  k_cast<<<4096, 256, 0, stream>>>(Whh0, Whh0b, 4194304);
  k_cast2<<<4096, 256, 0, stream>>>(Wih1, Wcat1, 0);                       // Wcat1[:, 0:1024]
  k_cast2<<<4096, 256, 0, stream>>>(Whh1, Wcat1, 1024);                    // Wcat1[:, 1024:2048]
  k_transpose_cast<<<4096, 256, 0, stream>>>(Wph, WphT, 1024, 4096);       // WphT[v][k]

  k_fused<<<256, 512, 0, stream>>>(Whh0b, Wcat1, xpbuf, bih0, bhh0, bih1, bhh1,
                                   h1seq, h2seq, flags);

  k_gemm<<<4096, 256, 0, stream>>>(h2seq, WphT, 128, d_out, bp, 1);        // logits (fp32)
}

// Round 14
// 2231.723 us; speedup vs baseline: 1.5587x; 1.0131x over previous
//
#include <hip/hip_runtime.h>
#include <cstdint>

typedef short bf16x8 __attribute__((ext_vector_type(8)));
typedef float f32x4 __attribute__((ext_vector_type(4)));
typedef unsigned u32x2 __attribute__((ext_vector_type(2)));

__device__ __forceinline__ unsigned short f2bf(float f){
  unsigned u = __float_as_uint(f);
  u = u + 0x7fffu + ((u >> 16) & 1u);      // RNE
  return (unsigned short)(u >> 16);
}
__device__ __forceinline__ float bf2f(unsigned short h){
  return __uint_as_float(((unsigned)h) << 16);
}

__device__ __forceinline__ void gld_lds16(const void* g, void* l){
  __builtin_amdgcn_global_load_lds((const __attribute__((address_space(1))) unsigned*)g,
                                   (__attribute__((address_space(3))) unsigned*)l, 16, 0, 0);
}

// L2-bypassing (LLC-coherent) ops — used ONLY for publish + flag polling
__device__ __forceinline__ void gstore8_cc(void* p, u32x2 v){
  asm volatile("global_store_dwordx2 %0, %1, off sc0 sc1" :: "v"(p), "v"(v) : "memory");
}
__device__ __forceinline__ void wait_vm0(){
  asm volatile("s_waitcnt vmcnt(0)" ::: "memory");
  __builtin_amdgcn_sched_barrier(0);
}

// all 64 flags (int) >= t ; one dword per lane
__device__ __forceinline__ void pollwait64(const int* f, int t, int lane){
  const int* p = f + lane;
  for (;;){
    int v;
    asm volatile("global_load_dword %0, %1, off sc0 sc1\n\ts_waitcnt vmcnt(0)"
                 : "=v"(v) : "v"(p) : "memory");
    if (__all(v >= t)) break;
    __builtin_amdgcn_s_sleep(2);
  }
}

// ---------------- elementwise f32 -> bf16 cast ----------------
__global__ __launch_bounds__(256)
void k_cast(const float* __restrict__ in, unsigned short* __restrict__ out, int n){
  int i = (blockIdx.x * 256 + threadIdx.x) * 4;
  if (i + 3 < n){
    float4 v = *(const float4*)(in + i);
    ushort4 u;
    u.x = f2bf(v.x); u.y = f2bf(v.y); u.z = f2bf(v.z); u.w = f2bf(v.w);
    *(ushort4*)(out + i) = u;
  }
}

// ---------------- cast f32 [4096][1024] into bf16 [4096][2048] at column offset ----------------
__global__ __launch_bounds__(256)
void k_cast2(const float* __restrict__ in, unsigned short* __restrict__ out, int coloff){
  int i = (blockIdx.x * 256 + threadIdx.x) * 4;
  if (i + 3 < 4194304){
    float4 v = *(const float4*)(in + i);
    ushort4 u;
    u.x = f2bf(v.x); u.y = f2bf(v.y); u.z = f2bf(v.z); u.w = f2bf(v.w);
    int r = i >> 10, c = i & 1023;
    *(ushort4*)(out + (size_t)r * 2048 + coloff + c) = u;
  }
}

// ---------------- transpose + cast: in f32 [R][C] -> out bf16 [C][R] ----------------
__global__ __launch_bounds__(256)
void k_transpose_cast(const float* __restrict__ in, unsigned short* __restrict__ out,
                      int R, int C){
  __shared__ float tile[32][33];
  int tpr = C >> 5;
  int r0 = (blockIdx.x / tpr) * 32, c0 = (blockIdx.x % tpr) * 32;
  int lc = threadIdx.x & 31, lr = threadIdx.x >> 5;
  #pragma unroll
  for (int it = 0; it < 4; ++it)
    tile[lr + it*8][lc] = in[(size_t)(r0 + lr + it*8) * C + c0 + lc];
  __syncthreads();
  #pragma unroll
  for (int it = 0; it < 4; ++it){
    int oc = lr + it*8;
    out[(size_t)(c0 + oc) * R + r0 + lc] = f2bf(tile[lc][oc]);
  }
}

// ---------------- embedding gather: xp0[t][r][b] = Wt0[x[b][t]][r] (bf16) ----------------
__global__ __launch_bounds__(256)
void k_gather(const unsigned short* __restrict__ Wt0, const int* __restrict__ x,
              unsigned short* __restrict__ xp){
  __shared__ unsigned short tile[32][520];
  __shared__ int tok[32];
  const int tid = threadIdx.x;
  const int t = blockIdx.x >> 3, rbase = (blockIdx.x & 7) * 512;
  if (tid < 32) tok[tid] = x[tid * 512 + t];
  __syncthreads();
  for (int b = 0; b < 32; ++b){
    unsigned v = *(const unsigned*)(Wt0 + (size_t)tok[b] * 4096 + rbase + tid * 2);
    *(unsigned*)&tile[b][tid * 2] = v;
  }
  __syncthreads();
  #pragma unroll
  for (int i = 0; i < 2; ++i){
    int rl = tid + i * 256;
    unsigned short vals[32];
    #pragma unroll
    for (int b = 0; b < 32; ++b) vals[b] = tile[b][rl];
    char* dst = (char*)xp + ((size_t)t * 131072 + (size_t)(rbase + rl) * 32) * 2;
    #pragma unroll
    for (int q = 0; q < 4; ++q){
      uint4 w;
      w.x = (unsigned)vals[q*8+0] | ((unsigned)vals[q*8+1] << 16);
      w.y = (unsigned)vals[q*8+2] | ((unsigned)vals[q*8+3] << 16);
      w.z = (unsigned)vals[q*8+4] | ((unsigned)vals[q*8+5] << 16);
      w.w = (unsigned)vals[q*8+6] | ((unsigned)vals[q*8+7] << 16);
      *(uint4*)(dst + q * 16) = w;
    }
  }
}

// ---------------- fused persistent 2-layer LSTM, TWO independent batch pipelines ----------------
// 256 blocks x 512 thr, 1 block/CU. Batch split into 2 independent groups of 16.
// Per layer per group: 64 blocks x (16 hidden units x 16 batches). XCD-locality decode
// (R13-proven, FETCH 430->255MB). SINGLE CHANGE vs R13 champion: gate-exchange buffer gl
// de-aliased to lds+96KB (disjoint from the <=64KB B-tile) -> barrier C removed (4
// barriers/step). Ordering proof: per-wave program order MFMA->gl-write + barrier D
// ensures all tile reads complete before D; next staging begins only after E->A.
template<int L1R>
__device__ __forceinline__ void run_lstm8(
    const unsigned short* __restrict__ Wb,      // bf16 [4096][KE]
    const unsigned short* __restrict__ xp,      // L0 only
    const float* __restrict__ b_ih, const float* __restrict__ b_hh,
    unsigned short* __restrict__ h_self,        // own layer output [512][32][1024]
    const unsigned short* __restrict__ h_in,    // L1: h1seq
    int* __restrict__ flag_self, const int* __restrict__ flag_in,
    int jslot, int gbase, char* lds)
{
  constexpr int KE  = L1R ? 2048 : 1024;   // K elems
  constexpr int RS  = KE * 2;              // row stride bytes (W and LDS tile)
  constexpr int KB2 = KE / 64;             // MFMA k-steps per wave (K split by 2)

  const int tid = threadIdx.x, lane = tid & 63, wv = tid >> 6;
  const int wv_k = wv & 1, wv_m = wv >> 1;           // K half, M-tile (= gate)
  const int l15 = lane & 15, l4 = (lane >> 4) & 3;
  const int jbase = jslot * 16;

  // A fragments in registers: gate wv_m, unit rows jbase..+16, K half wv_k
  bf16x8 afr[KB2];
  {
    const int grow = wv_m * 1024 + jbase + l15;
    const char* wrow = (const char*)Wb + (size_t)grow * RS + wv_k * KE + l4 * 16;
    #pragma unroll
    for (int i = 0; i < KB2; ++i) afr[i] = *(const bf16x8*)(wrow + i * 64);
  }

  const int ab = tid >> 4, aj = tid & 15;  // activation mapping (tid < 256): batch, unit
  const int jb = jbase + aj;
  float bi = 0.f, bff = 0.f, bg = 0.f, bo = 0.f;
  if (tid < 256){
    bi  = b_ih[jb]        + b_hh[jb];
    bff = b_ih[1024 + jb] + b_hh[1024 + jb];
    bg  = b_ih[2048 + jb] + b_hh[2048 + jb];
    bo  = b_ih[3072 + jb] + b_hh[3072 + jb];
  }
  float c = 0.f;
  float* gl = (float*)(lds + 98304);       // de-aliased gate exchange [2][64][17] (8.7KB at 96KB)
  const size_t bbase = (size_t)l15 * RS;   // batch row l15 (16 rows)
  const int bswz = (l15 & 7) << 4;
  const int kofs0 = wv_k * KE + l4 * 16;
  const f32x4 zero = {0.f, 0.f, 0.f, 0.f};

  for (int t = 0; t < 512; ++t){
    // xp prefetch into regs (L0, activation threads) — overlaps the poll
    float xr0 = 0.f, xr1 = 0.f, xr2 = 0.f, xr3 = 0.f;
    if (!L1R && tid < 256){
      const unsigned short* xpt = xp + (size_t)t * 131072 + gbase + ab;
      xr0 = bf2f(xpt[(size_t)jb * 32]);
      xr1 = bf2f(xpt[(size_t)(1024 + jb) * 32]);
      xr2 = bf2f(xpt[(size_t)(2048 + jb) * 32]);
      xr3 = bf2f(xpt[(size_t)(3072 + jb) * 32]);
    }

    // dataflow wait (wave 0 only; sequential polls — champion-proven order)
    if (wv == 0){
      if (L1R){
        pollwait64(flag_in,   t,     lane);   // h1[t] (group) ready
        pollwait64(flag_self, t - 1, lane);   // h2[t-1] (group) ready
      } else {
        pollwait64(flag_in,   t - 1, lane);   // h1[t-1] (group) ready
      }
    }
    __syncthreads();   // A: poll done; tile free (all reads finished before prev D)

    // stage B into LDS: cached global_load_lds, pre-swizzled source (16 rows = 32KB/region)
    if (!L1R){
      if (t == 0){
        #pragma unroll
        for (int it = 0; it < 4; ++it)
          *(f32x4*)(lds + it * 8192 + tid * 16) = zero;
      } else {
        const char* hp = (const char*)h_self + (size_t)(t - 1) * 65536 + (size_t)gbase * 2048;
        #pragma unroll
        for (int it = 0; it < 4; ++it){
          int u = it * 8192 + tid * 16;
          int b = u >> 11, kb = u & 2047;
          gld_lds16(hp + (size_t)b * 2048 + (kb ^ ((b & 7) << 4)), lds + u);
        }
      }
    } else {
      const char* hA = (const char*)h_in + (size_t)t * 65536 + (size_t)gbase * 2048;  // h1[t] -> lower K half
      #pragma unroll
      for (int it = 0; it < 4; ++it){
        int u = it * 8192 + tid * 16;
        int b = u >> 11, kb = u & 2047;
        gld_lds16(hA + (size_t)b * 2048 + (kb ^ ((b & 7) << 4)), lds + (size_t)b * 4096 + kb);
      }
      if (t == 0){
        #pragma unroll
        for (int it = 0; it < 4; ++it){
          int u = it * 8192 + tid * 16;
          int b = u >> 11, kb = u & 2047;
          *(f32x4*)(lds + (size_t)b * 4096 + 2048 + kb) = zero;
        }
      } else {
        const char* hB = (const char*)h_self + (size_t)(t - 1) * 65536 + (size_t)gbase * 2048; // h2[t-1] -> upper
        #pragma unroll
        for (int it = 0; it < 4; ++it){
          int u = it * 8192 + tid * 16;
          int b = u >> 11, kb = u & 2047;
          gld_lds16(hB + (size_t)b * 2048 + (kb ^ ((b & 7) << 4)), lds + (size_t)b * 4096 + 2048 + kb);
        }
      }
    }
    __syncthreads();   // B: staging visible (compiler drains vmcnt/lgkmcnt)

    // MFMA over this wave's K half, 4 independent chains (k-step parity), one N-tile
    f32x4 a0 = zero, a1 = zero, a2 = zero, a3 = zero;
    #pragma unroll
    for (int i = 0; i < KB2; i += 4){
      bf16x8 b0 = *(const bf16x8*)(lds + bbase + (((i + 0) * 64 + kofs0) ^ bswz));
      bf16x8 b1 = *(const bf16x8*)(lds + bbase + (((i + 1) * 64 + kofs0) ^ bswz));
      bf16x8 b2 = *(const bf16x8*)(lds + bbase + (((i + 2) * 64 + kofs0) ^ bswz));
      bf16x8 b3 = *(const bf16x8*)(lds + bbase + (((i + 3) * 64 + kofs0) ^ bswz));
      a0 = __builtin_amdgcn_mfma_f32_16x16x32_bf16(afr[i + 0], b0, a0, 0, 0, 0);
      a1 = __builtin_amdgcn_mfma_f32_16x16x32_bf16(afr[i + 1], b1, a1, 0, 0, 0);
      a2 = __builtin_amdgcn_mfma_f32_16x16x32_bf16(afr[i + 2], b2, a2, 0, 0, 0);
      a3 = __builtin_amdgcn_mfma_f32_16x16x32_bf16(afr[i + 3], b3, a3, 0, 0, 0);
    }
    a0 += a1; a2 += a3; a0 += a2;
    // (barrier C removed: gl is disjoint from the tile; D orders gl write->read and
    //  by program order guarantees all tile reads complete before D)

    // gate exchange (per K-half partials): gl[kh][srow 64][col 17]
    {
      int srow = wv_m * 16 + l4 * 4;
      float* g = gl + wv_k * 1088 + srow * 17 + l15;
      g[0] = a0[0]; g[17] = a0[1]; g[34] = a0[2]; g[51] = a0[3];
    }
    __syncthreads();   // D

    // activation + state update + packed 8B publish (threads 0..255)
    if (tid < 256){
      float gi = gl[aj * 17 + ab]        + gl[1088 + aj * 17 + ab]        + xr0 + bi;
      float gf = gl[(16 + aj) * 17 + ab] + gl[1088 + (16 + aj) * 17 + ab] + xr1 + bff;
      float gg = gl[(32 + aj) * 17 + ab] + gl[1088 + (32 + aj) * 17 + ab] + xr2 + bg;
      float go = gl[(48 + aj) * 17 + ab] + gl[1088 + (48 + aj) * 17 + ab] + xr3 + bo;
      float i_ = 1.f / (1.f + __expf(-gi));
      float f_ = 1.f / (1.f + __expf(-gf));
      float g_ = 1.f - 2.f / (1.f + __expf(2.f * gg));
      float o_ = 1.f / (1.f + __expf(-go));
      c = f_ * c + i_ * g_;
      float h_ = o_ * (1.f - 2.f / (1.f + __expf(2.f * c)));
      unsigned p = (unsigned)f2bf(h_);
      unsigned w = p | (((unsigned)__shfl_xor((int)p, 1) & 0xFFFFu) << 16);  // units (aj, aj+1)
      unsigned d1 = (unsigned)__shfl_xor((int)w, 2);                          // units (aj+2, aj+3)
      if ((aj & 3) == 0){
        u32x2 W2; W2.x = w; W2.y = d1;
        gstore8_cc((char*)h_self + (size_t)t * 65536 + (size_t)(gbase + ab) * 2048
                   + (size_t)(jbase + aj) * 2, W2);
      }
    }
    wait_vm0();        // own wave's publish stores retired at LLC
    __syncthreads();   // E: all waves' stores retired; gl reads done
    if (tid == 0)
      __hip_atomic_store(flag_self + jslot, t, __ATOMIC_RELAXED, __HIP_MEMORY_SCOPE_AGENT);
  }
}

__global__ __launch_bounds__(512, 1)
void k_fused(const unsigned short* __restrict__ Whh0b,
             const unsigned short* __restrict__ Wcat1,
             const unsigned short* __restrict__ xp,
             const float* __restrict__ bih0, const float* __restrict__ bhh0,
             const float* __restrict__ bih1, const float* __restrict__ bhh1,
             unsigned short* __restrict__ h1seq, unsigned short* __restrict__ h2seq,
             int* __restrict__ flags)
{
  __shared__ char lds[131072];   // forces 1 block/CU (tile <=64KB; gl at +96KB)
  __threadfence();     // one-time L1/L2 invalidate: clear any stale pre-run lines
  // XCD-locality decode (round-robin xcd = blockIdx % 8 — confirmed by R13 FETCH drop):
  //   bid%8 in {0,1} -> (L0,g0) on XCDs 0,1 ; {2,3} -> (L1,g0) ; {4,5} -> (L0,g1) ; {6,7} -> (L1,g1)
  const int bid = blockIdx.x;
  const int grp   = (bid >> 2) & 1;
  const int layer = (bid >> 1) & 1;
  const int jslot = ((bid >> 3) << 1) | (bid & 1);   // 0..63 within team
  const int gbase = grp * 16;
  int* f0 = flags + grp * 128;         // layer-0 flags for this group (64 ints)
  int* f1 = flags + 256 + grp * 128;   // layer-1 flags for this group
  if (layer == 0)
    run_lstm8<0>(Whh0b, xp, bih0, bhh0, h1seq, nullptr, f0, f0, jslot, gbase, lds);
  else
    run_lstm8<1>(Wcat1, nullptr, bih1, bhh1, h2seq, h1seq, f1, f0, jslot, gbase, lds);
}

// ---------------- NT GEMM: C[m][n] = sum_k A[m][k]*B[n][k], K=1024, tile 128x128 ----------------
// mode 1: out f32 [b][t][v] (tb = m: b = tb&31, t = tb>>5, v = n) + bias bp[v]
__global__ __launch_bounds__(256, 2)
void k_gemm(const unsigned short* __restrict__ A,
            const unsigned short* __restrict__ B,
            int Mtiles, void* __restrict__ outp,
            const float* __restrict__ bp, int mode)
{
  __shared__ char As[16384];
  __shared__ char Bs[16384];
  const int tid = threadIdx.x, lane = tid & 63, wv = tid >> 6;
  const int mq = (wv >> 1) * 64, nq = (wv & 1) * 64;
  const int l15 = lane & 15, l4 = (lane >> 4) & 3;
  const int mt = blockIdx.x % Mtiles, nt = blockIdx.x / Mtiles;
  const char* Abase = (const char*)A + (size_t)(mt * 128) * 2048;
  const char* Bbase = (const char*)B + (size_t)(nt * 128) * 2048;
  const f32x4 zero = {0.f, 0.f, 0.f, 0.f};
  f32x4 acc[4][4];
  #pragma unroll
  for (int i = 0; i < 4; ++i)
    #pragma unroll
    for (int j = 0; j < 4; ++j) acc[i][j] = zero;

  for (int kt = 0; kt < 16; ++kt){
    __syncthreads();
    #pragma unroll
    for (int p = 0; p < 4; ++p){
      int o = p * 4096 + tid * 16;
      int row = o >> 7, kb = o & 127;
      gld_lds16(Abase + (size_t)row * 2048 + kt * 128 + (kb ^ ((row & 7) << 4)), As + o);
    }
    #pragma unroll
    for (int p = 0; p < 4; ++p){
      int o = p * 4096 + tid * 16;
      int row = o >> 7, kb = o & 127;
      gld_lds16(Bbase + (size_t)row * 2048 + kt * 128 + (kb ^ ((row & 7) << 4)), Bs + o);
    }
    __syncthreads();
    #pragma unroll
    for (int kk = 0; kk < 2; ++kk){
      bf16x8 af[4], bfr[4];
      #pragma unroll
      for (int i = 0; i < 4; ++i){
        int row = mq + i * 16 + l15;
        int kbyte = kk * 64 + l4 * 16;
        af[i]  = *(const bf16x8*)(As + row * 128 + (kbyte ^ ((row & 7) << 4)));
        int nrow = nq + i * 16 + l15;
        bfr[i] = *(const bf16x8*)(Bs + nrow * 128 + (kbyte ^ ((nrow & 7) << 4)));
      }
      #pragma unroll
      for (int i = 0; i < 4; ++i)
        #pragma unroll
        for (int j = 0; j < 4; ++j)
          acc[i][j] = __builtin_amdgcn_mfma_f32_16x16x32_bf16(af[i], bfr[j], acc[i][j], 0, 0, 0);
    }
  }

  if (mode == 0){
    unsigned short* o16 = (unsigned short*)outp;
    #pragma unroll
    for (int i = 0; i < 4; ++i)
      #pragma unroll
      for (int j = 0; j < 4; ++j){
        int n = nt * 128 + nq + j * 16 + l15;
        int tt = n >> 5, bc = n & 31;
        #pragma unroll
        for (int r = 0; r < 4; ++r){
          int m = mt * 128 + mq + i * 16 + l4 * 4 + r;
          o16[(size_t)tt * 131072 + (size_t)m * 32 + bc] = f2bf(acc[i][j][r]);
        }
      }
  } else {
    float* of = (float*)outp;
    #pragma unroll
    for (int j = 0; j < 4; ++j){
      int v = nt * 128 + nq + j * 16 + l15;
      float bias = bp[v];
      #pragma unroll
      for (int i = 0; i < 4; ++i)
        #pragma unroll
        for (int r = 0; r < 4; ++r){
          int tb = mt * 128 + mq + i * 16 + l4 * 4 + r;
          int tt = tb >> 5, bb2 = tb & 31;
          of[(size_t)bb2 * 2097152 + (size_t)tt * 4096 + v] = acc[i][j][r] + bias;
        }
    }
  }
}

extern "C" void kernel_launch(void* const* d_in, const int* in_sizes, int n_in,
                              void* d_out, int out_size, void* d_ws, size_t ws_size,
                              hipStream_t stream)
{
  const int*   x    = (const int*)  d_in[0];
  const float* Wih0 = (const float*)d_in[1];
  const float* Whh0 = (const float*)d_in[2];
  const float* bih0 = (const float*)d_in[3];
  const float* bhh0 = (const float*)d_in[4];
  const float* Wih1 = (const float*)d_in[5];
  const float* Whh1 = (const float*)d_in[6];
  const float* bih1 = (const float*)d_in[7];
  const float* bhh1 = (const float*)d_in[8];
  const float* Wph  = (const float*)d_in[9];
  const float* bp   = (const float*)d_in[10];

  char* ws = (char*)d_ws;
  int* flags = (int*)ws;                      // 4 x 64 ints at 512B spacing (2KB total)
  unsigned short* Whh0b = (unsigned short*)(ws + 4096);                    // 8MB
  char* regA = ws + 4096 + 8388608;                                        // 32MB region
  unsigned short* Wt0   = (unsigned short*)regA;                           // 32MB (pre-phase)
  unsigned short* Wcat1 = (unsigned short*)regA;                           // 16MB (reuses Wt0)
  unsigned short* WphT  = (unsigned short*)(regA + 16777216);              // 8MB
  unsigned short* h1seq = (unsigned short*)(ws + 4096 + 8388608 + 33554432);            // 32MB
  unsigned short* h2seq = (unsigned short*)(ws + 4096 + 8388608 + 33554432 + 33554432); // 32MB
  unsigned short* xpbuf = (unsigned short*)d_out;  // xp0 scratch inside d_out (rewritten at end)

  hipMemsetAsync(d_ws, 0xFF, 2048, stream);        // all flag arrays := -1

  k_transpose_cast<<<16384, 256, 0, stream>>>(Wih0, Wt0, 4096, 4096);      // Wt0[v][r]
  k_gather<<<4096, 256, 0, stream>>>(Wt0, x, xpbuf);                       // xp0 -> d_out
  k_cast<<<4096, 256, 0, stream>>>(Whh0, Whh0b, 4194304);
  k_cast2<<<4096, 256, 0, stream>>>(Wih1, Wcat1, 0);                       // Wcat1[:, 0:1024]
  k_cast2<<<4096, 256, 0, stream>>>(Whh1, Wcat1, 1024);                    // Wcat1[:, 1024:2048]
  k_transpose_cast<<<4096, 256, 0, stream>>>(Wph, WphT, 1024, 4096);       // WphT[v][k]

  k_fused<<<256, 512, 0, stream>>>(Whh0b, Wcat1, xpbuf, bih0, bhh0, bih1, bhh1,
                                   h1seq, h2seq, flags);

  k_gemm<<<4096, 256, 0, stream>>>(h2seq, WphT, 128, d_out, bp, 1);        // logits (fp32)
}